// Round 1
// baseline (160.890 us; speedup 1.0000x reference)
//
#include <hip/hip_runtime.h>
#include <hip/hip_bf16.h>
#include <math.h>

#define N_TOT 8192
#define HALF_N 4096
#define D_DIM 512
#define BM 128
#define BK 64          // fp8 bytes per K-chunk; 8 K-iterations, 64B LDS rows
#define NKIT (D_DIM / BK)
#define NTILES 2080    // 64*65/2 upper-triangle 128x128 tiles

// s_waitcnt imm: vmcnt[3:0] | expcnt<<4 | lgkmcnt<<8 (expcnt/lgkmcnt = max -> unconstrained)
#define WAIT_VM4 0xF74
#define WAIT_VM0 0xF70

typedef float f32x16 __attribute__((ext_vector_type(16)));
typedef int   i32x4  __attribute__((ext_vector_type(4)));
typedef int   i32x8  __attribute__((ext_vector_type(8)));

typedef __attribute__((address_space(1))) unsigned int g_u32;
typedef __attribute__((address_space(3))) unsigned int l_u32;

// Kernel 1: L2-normalize rows of [p1;p2] -> fp8 e4m3 Z in k-PERMUTED layout
// (validated R9/R11): within each 64B k-block, source byte k (q=(k>>3)&3,
// h=(k>>5)&1) stored at q*16 + h*8 + (k&7). Both GEMM operands use the same
// bijection, so dot products are unaffected regardless of the MFMA's internal
// hw-k ordering (A and B lane layouts share the same k-distribution).
__global__ __launch_bounds__(256) void k_normalize(
    const float* __restrict__ p1, const float* __restrict__ p2,
    unsigned char* __restrict__ zf8, float* __restrict__ rowsum,
    float* __restrict__ out)
{
    const int w = threadIdx.x >> 6;
    const int lane = threadIdx.x & 63;
    const int row = blockIdx.x * 4 + w;

    if (threadIdx.x < 4) rowsum[blockIdx.x * 4 + threadIdx.x] = 0.0f;
    if (blockIdx.x == 0 && threadIdx.x == 0) out[0] = 0.0f;

    const float* src = (row < HALF_N) ? p1 + (size_t)row * D_DIM
                                      : p2 + (size_t)(row - HALF_N) * D_DIM;
    float4 a = *(const float4*)(src + lane * 4);
    float4 b = *(const float4*)(src + 256 + lane * 4);
    float s = a.x*a.x + a.y*a.y + a.z*a.z + a.w*a.w
            + b.x*b.x + b.y*b.y + b.z*b.z + b.w*b.w;
    #pragma unroll
    for (int m = 1; m < 64; m <<= 1) s += __shfl_xor(s, m, 64);
    float inv = 1.0f / fmaxf(sqrtf(s), 1e-8f);

    int pk0 = __builtin_amdgcn_cvt_pk_fp8_f32(a.x * inv, a.y * inv, 0, false);
    pk0     = __builtin_amdgcn_cvt_pk_fp8_f32(a.z * inv, a.w * inv, pk0, true);
    int pk1 = __builtin_amdgcn_cvt_pk_fp8_f32(b.x * inv, b.y * inv, 0, false);
    pk1     = __builtin_amdgcn_cvt_pk_fp8_f32(b.z * inv, b.w * inv, pk1, true);

    unsigned char* dst = zf8 + (size_t)row * D_DIM;
    const int o0 = lane * 4;
    const int o1 = 256 + lane * 4;
    const int d0 = (o0 & ~63) + ((o0 >> 3) & 3) * 16 + ((o0 >> 5) & 1) * 8 + (o0 & 4);
    const int d1 = (o1 & ~63) + ((o1 >> 3) & 3) * 16 + ((o1 >> 5) & 1) * 8 + (o1 & 4);
    *(int*)(dst + d0) = pk0;
    *(int*)(dst + d1) = pk1;
}

// Kernel 2: upper-triangle tiles of sim = Z*Z^T.
// ROUND 0 change: MFMA switched from 16x16x32 fp8 (bf16-rate, 2.2 PF class)
// to block-scaled v_mfma_f32_32x32x64_f8f6f4 with unit E8M0 scales (0x7F):
// numerically the same product, 2.14x pipe rate (4686 TF, m59), 8x fewer
// MFMA instructions (32/wave vs 256/wave). K=64 matches BK exactly, so the
// TRIPLE-buffered LDS + prefetch-distance-2 + counted `s_waitcnt vmcnt(4)`
// machinery (AITER "never vmcnt(0)" pattern) is unchanged, as is staging.
// Each lane reads 32 contiguous stored bytes = chunks {2h, 2h+1} through the
// existing chunk^((row>>1)&3) slot swizzle: 16-lane groups cover all 8
// bank-groups -> max 2-way aliasing (free, m136). k-permuted zf8 layout is a
// per-row bijection shared by A and B, so dot products are exact (R11 lesson).
__global__ __launch_bounds__(256, 4) void k_gemm(
    const unsigned char* __restrict__ zf8,
    float* __restrict__ rowsum, float* __restrict__ pos)
{
    __shared__ __align__(16) unsigned char As[3][BM * BK];  // 3 x 8 KB
    __shared__ __align__(16) unsigned char Bs[3][BM * BK];  // 3 x 8 KB

    const int tid = threadIdx.x;
    const int lane = tid & 63;
    const int w = tid >> 6;
    const int wr = w >> 1, wc = w & 1;
    const int r32 = lane & 31;      // MFMA 32x32 row/col within fragment
    const int hh = lane >> 5;       // k-half select (which 32B of the 64B row)

    // triangular block mapping: t -> (bx >= by)
    const int t = blockIdx.x;
    int bi = (int)((sqrtf(8.0f * (float)t + 1.0f) - 1.0f) * 0.5f);
    while ((bi + 1) * (bi + 2) / 2 <= t) ++bi;
    while (bi * (bi + 1) / 2 > t) --bi;
    const int bx = bi;                       // col tile (larger)
    const int by = t - bi * (bi + 1) / 2;    // row tile
    const bool isDiag = (bx == by);
    const bool hasPos = (bx - by == 32);
    const int rowBase = by * BM;
    const int colBase = bx * BM;

    // staging (R8/R11-proven): 16B chunks, dest chunk = tid / 256+tid,
    // LDS slot cc of row r holds source chunk cc ^ ((r>>1)&3).
    const int ci0 = tid;
    const int ci1 = 256 + tid;
    const int r0 = ci0 >> 2, cc0 = ci0 & 3;
    const int r1 = ci1 >> 2, cc1 = ci1 & 3;
    const int gc0 = cc0 ^ ((r0 >> 1) & 3);
    const int gc1 = cc1 ^ ((r1 >> 1) & 3);

    const unsigned char* gA0 = zf8 + (size_t)(rowBase + r0) * D_DIM + gc0 * 16;
    const unsigned char* gA1 = zf8 + (size_t)(rowBase + r1) * D_DIM + gc1 * 16;
    const unsigned char* gB0 = zf8 + (size_t)(colBase + r0) * D_DIM + gc0 * 16;
    const unsigned char* gB1 = zf8 + (size_t)(colBase + r1) * D_DIM + gc1 * 16;

    auto stage = [&](int buf, int kblk) {
        const int kb = kblk * BK;
        __builtin_amdgcn_global_load_lds((const g_u32*)(gA0 + kb), (l_u32*)&As[buf][ci0 * 16], 16, 0, 0);
        __builtin_amdgcn_global_load_lds((const g_u32*)(gA1 + kb), (l_u32*)&As[buf][ci1 * 16], 16, 0, 0);
        __builtin_amdgcn_global_load_lds((const g_u32*)(gB0 + kb), (l_u32*)&Bs[buf][ci0 * 16], 16, 0, 0);
        __builtin_amdgcn_global_load_lds((const g_u32*)(gB1 + kb), (l_u32*)&Bs[buf][ci1 * 16], 16, 0, 0);
    };

    f32x16 acc[2][2] = {};

    stage(0, 0);   // 4 vm ops (oldest)
    stage(1, 1);   // 4 vm ops

    #pragma unroll
    for (int it = 0; it < NKIT; it++) {
        const int cur = it % 3;
        // wait ONLY the 4 oldest loads (= buf[cur]); keep next iter's 4 in flight
        if (it + 1 < NKIT) __builtin_amdgcn_s_waitcnt(WAIT_VM4);
        else               __builtin_amdgcn_s_waitcnt(WAIT_VM0);
        __builtin_amdgcn_s_barrier();

        if (it + 2 < NKIT) stage((it + 2) % 3, it + 2);

        // Each fragment: 32 contiguous stored bytes = two ds_read_b128 through
        // the chunk swizzle. Byte j of operand = stored byte hh*32 + j.
        i32x8 aF[2], bF[2];
        #pragma unroll
        for (int i = 0; i < 2; i++) {
            const int ra = wr * 64 + i * 32 + r32;
            const int rb = wc * 64 + i * 32 + r32;
            const int sa = (ra >> 1) & 3;
            const int sb = (rb >> 1) & 3;
            i32x4 alo = *(const i32x4*)&As[cur][ra * BK + ((2 * hh)     ^ sa) * 16];
            i32x4 ahi = *(const i32x4*)&As[cur][ra * BK + ((2 * hh + 1) ^ sa) * 16];
            i32x4 blo = *(const i32x4*)&Bs[cur][rb * BK + ((2 * hh)     ^ sb) * 16];
            i32x4 bhi = *(const i32x4*)&Bs[cur][rb * BK + ((2 * hh + 1) ^ sb) * 16];
            aF[i] = __builtin_shufflevector(alo, ahi, 0, 1, 2, 3, 4, 5, 6, 7);
            bF[i] = __builtin_shufflevector(blo, bhi, 0, 1, 2, 3, 4, 5, 6, 7);
        }
        #pragma unroll
        for (int i = 0; i < 2; i++)
            #pragma unroll
            for (int j = 0; j < 2; j++)
                acc[i][j] = __builtin_amdgcn_mfma_scale_f32_32x32x64_f8f6f4(
                    aF[i], bF[j], acc[i][j],
                    0 /*cbsz: fp8 e4m3*/, 0 /*blgp: fp8 e4m3*/,
                    0, 127 /*scale A = 2^0*/, 0, 127 /*scale B = 2^0*/);
    }

    // Epilogue. C/D layout (32x32 family, m74/m101): col = lane&31,
    // row = (reg&3) + 8*(reg>>2) + 4*(lane>>5).
    float colacc[2] = {0.f, 0.f};
    #pragma unroll
    for (int i = 0; i < 2; i++) {
        #pragma unroll
        for (int reg = 0; reg < 16; reg++) {
            const int row = rowBase + wr * 64 + i * 32 + (reg & 3) + 8 * (reg >> 2) + 4 * hh;
            float rs = 0.0f;
            #pragma unroll
            for (int j = 0; j < 2; j++) {
                const int col = colBase + wc * 64 + j * 32 + r32;
                const float c = acc[i][j][reg];
                float e = __expf(c);
                if (isDiag && col == row) e = 0.0f;
                rs += e;
                colacc[j] += e;
                if (hasPos && col == row + HALF_N) { pos[row] = c; pos[col] = c; }
            }
            rs += __shfl_xor(rs, 1); rs += __shfl_xor(rs, 2);
            rs += __shfl_xor(rs, 4); rs += __shfl_xor(rs, 8);
            rs += __shfl_xor(rs, 16);
            if (r32 == 0) atomicAdd(&rowsum[row], rs);
        }
    }
    if (!isDiag) {
        #pragma unroll
        for (int j = 0; j < 2; j++) {
            float cs = colacc[j];
            cs += __shfl_xor(cs, 32);
            if (hh == 0) atomicAdd(&rowsum[colBase + wc * 64 + j * 32 + r32], cs);
        }
    }
}

// Kernel 3: mean over rows of (log(rowsum) - pos) -> scalar (out pre-zeroed).
__global__ __launch_bounds__(256) void k_finalize(
    const float* __restrict__ rowsum, const float* __restrict__ pos,
    float* __restrict__ out)
{
    const int t = threadIdx.x;
    const int i = blockIdx.x * 256 + t;
    float s = logf(rowsum[i]) - pos[i];
    #pragma unroll
    for (int m = 1; m < 64; m <<= 1) s += __shfl_xor(s, m, 64);
    __shared__ float red[4];
    if ((t & 63) == 0) red[t >> 6] = s;
    __syncthreads();
    if (t == 0)
        atomicAdd(out, (red[0] + red[1] + red[2] + red[3]) * (1.0f / (float)N_TOT));
}

extern "C" void kernel_launch(void* const* d_in, const int* in_sizes, int n_in,
                              void* d_out, int out_size, void* d_ws, size_t ws_size,
                              hipStream_t stream) {
    const float* p1 = (const float*)d_in[0];
    const float* p2 = (const float*)d_in[1];

    unsigned char* zf8 = (unsigned char*)d_ws;                          // 4 MB
    float* rowsum = (float*)((char*)d_ws + (size_t)N_TOT * D_DIM);      // 32 KB
    float* pos    = rowsum + N_TOT;                                     // 32 KB
    float* outp   = (float*)d_out;

    k_normalize<<<N_TOT / 4, 256, 0, stream>>>(p1, p2, zf8, rowsum, outp);
    k_gemm<<<NTILES, 256, 0, stream>>>(zf8, rowsum, pos);
    k_finalize<<<N_TOT / 256, 256, 0, stream>>>(rowsum, pos, outp);
}